// Round 12
// baseline (808.547 us; speedup 1.0000x reference)
//
#include <hip/hip_runtime.h>
#include <math.h>

#define MASKN 1023

typedef unsigned short ushort_t;
typedef __attribute__((ext_vector_type(8))) short short8;
typedef __attribute__((ext_vector_type(4))) float floatx4;
typedef __attribute__((ext_vector_type(4))) unsigned short us4v;   // 8B-aligned bf16x4

// tanh-form GELU; v_rcp_f32 instead of IEEE div (R8, ~1ulp, fine for approx gelu)
__device__ __forceinline__ float gelu_f(float x) {
    float x2 = x * x;
    float inner = fmaf(0.044715f * x, x2, x);
    float t = exp2f(inner * -2.302089214f);   // 2^(-2*0.7978845608*log2(e)*inner)
    return x * __builtin_amdgcn_rcpf(1.0f + t);
}

// ---- bf16 storage helpers (compute stays fp32) ----
__device__ __forceinline__ float bf2f(ushort_t h) {
    return __uint_as_float(((unsigned int)h) << 16);
}
__device__ __forceinline__ ushort_t f2bf(float f) {
    unsigned int u = __float_as_uint(f);
    u += 0x7FFFu + ((u >> 16) & 1u);   // round to nearest even
    return (ushort_t)(u >> 16);
}
struct us4 { ushort_t x, y, z, w; };

// pack 2 f32 -> 2 bf16 in ONE v_cvt_pk_bf16_f32 (RNE, same as manual path)
__device__ __forceinline__ unsigned int pk2bf(float lo, float hi) {
    unsigned int r;
    asm("v_cvt_pk_bf16_f32 %0, %1, %2" : "=v"(r) : "v"(lo), "v"(hi));
    return r;
}

__device__ __forceinline__ void st4(ushort_t* p, float4 v) {
    uint2 w;
    w.x = pk2bf(v.x, v.y);
    w.y = pk2bf(v.z, v.w);
    *(uint2*)p = w;
}

// async global->LDS, 16 B per lane; LDS dest = wave-uniform base + lane*16 (HW),
// global src is PER-LANE (this is how the swizzled staging works).
__device__ __forceinline__ void async16(ushort_t* l, const ushort_t* g) {
    __builtin_amdgcn_global_load_lds(
        (const __attribute__((address_space(1))) void*)g,
        (__attribute__((address_space(3))) void*)l, 16, 0, 0);
}

// ---------------- twiddle step table for k_f2 / k_i1
__global__ void k_fill_tw(float* __restrict__ ct, float* __restrict__ st) {
    int j = blockIdx.x * 256 + threadIdx.x;   // 0..1023
    float ang = (float)j * (6.283185307179586f / 1024.0f);
    float s, c;
    sincosf(ang, &s, &c);
    ct[j] = c; st[j] = s;
}

// ---------------- T1 table
__global__ void k_fill_T1(ushort_t* __restrict__ T1h, ushort_t* __restrict__ T1l) {
    int idx = blockIdx.x * 256 + threadIdx.x;   // 0..65535
    int k2p = idx >> 10, y = idx & 1023;
    int k2 = k2p >> 1;
    float ang = (float)((k2 * y) & MASKN) * (6.283185307179586f / 1024.0f);
    float s, c;
    sincosf(ang, &s, &c);
    float v = (k2p & 1) ? -s : c;
    ushort_t h = f2bf(v);
    T1h[idx] = h;
    T1l[idx] = f2bf(v - bf2f(h));
}

// ---------------- T2p table (R12: k2-PARITY-SPLIT layout for the DFT symmetry)
// T2p[n2][col], n2 in [0,512): col<32 = even-k2 coeffs, col>=32 = odd-k2.
// Within a block: w = col&31 -> k2 = (w>>1)*2 + (col>>5), e = w&1 (0=cos,1=-sin).
// Rows n2+512 are NOT stored: C[n2+512] = E[n2] - O[n2] by (-1)^k2 symmetry.
__global__ void k_fill_T2(ushort_t* __restrict__ T2h, ushort_t* __restrict__ T2l) {
    int idx = blockIdx.x * 256 + threadIdx.x;   // 0..32767
    int n2 = idx >> 6, col = idx & 63;
    int w = col & 31;
    int k2 = ((w >> 1) << 1) + (col >> 5);
    float ang = (float)((k2 * n2) & MASKN) * (6.283185307179586f / 1024.0f);
    float s, c;
    sincosf(ang, &s, &c);
    float v = (w & 1) ? -s : c;
    ushort_t h = f2bf(v);
    T2h[idx] = h;
    T2l[idx] = f2bf(v - bf2f(h));
}

// ---------------- wT tables: wT[l][d][c] = w_l[c][d], hi/lo
__global__ void k_fill_wT(const float* __restrict__ w1, const float* __restrict__ w2,
        const float* __restrict__ w3, const float* __restrict__ w4,
        ushort_t* __restrict__ wTh, ushort_t* __restrict__ wTl) {
    int l = blockIdx.y;
    int i = blockIdx.x * 256 + threadIdx.x;   // 0..4095
    int d = i >> 6, c = i & 63;
    const float* w = (l == 0) ? w1 : (l == 1) ? w2 : (l == 2) ? w3 : w4;
    float v = w[c * 64 + d];
    ushort_t h = f2bf(v);
    wTh[l * 4096 + i] = h;
    wTl[l * 4096 + i] = f2bf(v - bf2f(h));
}

// ---------------- shallow
__global__ __launch_bounds__(256) void k_shallow(const float* __restrict__ in,
        const float* __restrict__ Wsh, const float* __restrict__ bsh,
        ushort_t* __restrict__ vt) {
    int tid = blockIdx.x * 256 + threadIdx.x;
    int p = tid >> 4, c0 = (tid & 15) << 2;
    float a0 = in[p * 2], a1 = in[p * 2 + 1];
    float4 w0 = *(const float4*)&Wsh[c0];
    float4 w1 = *(const float4*)&Wsh[64 + c0];
    float4 b  = *(const float4*)&bsh[c0];
    float4 r;
    r.x = gelu_f(fmaf(a0, w0.x, fmaf(a1, w1.x, b.x)));
    r.y = gelu_f(fmaf(a0, w0.y, fmaf(a1, w1.y, b.y)));
    r.z = gelu_f(fmaf(a0, w0.z, fmaf(a1, w1.z, b.z)));
    r.w = gelu_f(fmaf(a0, w0.w, fmaf(a1, w1.w, b.w)));
    st4(&vt[(size_t)p * 64 + c0], r);
}

// ---------------- F1 (MFMA): gT[x][c][k2p] = sum_y vt[x][y][c] * T1[k2p][y]
// (R9 structure: counted s_waitcnt vmcnt(2) + raw s_barrier, vt pf 2 phases
// ahead, t1s 1 phase ahead -- proven, unchanged)
#define VS1 72   // vs row stride in shorts (144 B -> bank 4*lm, 2-way = free)
__global__ __launch_bounds__(256, 3) void k_f1(const ushort_t* __restrict__ vt,
        const ushort_t* __restrict__ T1h, const ushort_t* __restrict__ T1l,
        float* __restrict__ gT) {
    __shared__ __align__(16) ushort_t t1s[2][8192];      // [buf][h:0..4095 | l:4096..8191] shorts
    __shared__ __align__(16) ushort_t vs[2][64 * VS1];   // [buf][c][y] transposed vt tile
    int t = threadIdx.x;
    int x = blockIdx.x;
    int wv = t >> 6, lane = t & 63;
    int lm = lane & 15, quad = lane >> 4;
    int lrow = t & 63, cq = (t >> 6) * 16;               // staging map: 64 y-rows x 4 c-quarters
    const ushort_t* vrow = vt + (size_t)x * 65536;

    floatx4 acc[4];
    #pragma unroll
    for (int nt = 0; nt < 4; ++nt) acc[nt] = (floatx4)(0.f);

    uint4 pf[2][2];   // pf[hc&1] = vt rows for chunk hc, loaded 2 chunks ahead
    // prologue: t1s(0) stage FIRST (older in vmcnt queue than any pf -> the
    // scatter's pf wait also covers it), then pf(0), pf(1).
    #pragma unroll
    for (int i = 0; i < 4; ++i) {
        int j = (wv * 4 + i) * 64 + lane;            // 0..1023 16B-units (h then l)
        int jj = j & 511;
        int r = jj >> 3, du = jj & 7, su = du ^ (r & 7);
        const ushort_t* src = ((j < 512) ? T1h : T1l) + (size_t)r * 1024 + su * 8;
        async16(&t1s[0][(wv * 4 + i) * 512], src);
    }
    __builtin_amdgcn_sched_barrier(0);
    {
        const ushort_t* s0 = vrow + (size_t)lrow * 64 + cq;
        pf[0][0] = *(const uint4*)(s0);
        pf[0][1] = *(const uint4*)(s0 + 8);
        const ushort_t* s1 = vrow + (size_t)(64 + lrow) * 64 + cq;
        pf[1][0] = *(const uint4*)(s1);
        pf[1][1] = *(const uint4*)(s1 + 8);
    }
    __builtin_amdgcn_sched_barrier(0);

    for (int hc = 0; hc < 16; ++hc) {
        int b = hc & 1;
        // scatter pf[b] (chunk hc) transposed into wave-private vs[b]
        #pragma unroll
        for (int i = 0; i < 2; ++i) {
            union { uint4 u; ushort_t e[8]; } uv;
            uv.u = pf[b][i];
            #pragma unroll
            for (int j = 0; j < 8; ++j)
                vs[b][(cq + i * 8 + j) * VS1 + lrow] = uv.e[j];
        }
        __builtin_amdgcn_sched_barrier(0);
        // T4 counted wait: complete t1s[b] (staged last iter); leave chunk
        // hc+1's 2 vt loads in flight (they don't exist on the last iter).
        if (hc < 15) asm volatile("s_waitcnt vmcnt(2)" ::: "memory");
        else         asm volatile("s_waitcnt vmcnt(0)" ::: "memory");
        __builtin_amdgcn_sched_barrier(0);
        __builtin_amdgcn_s_barrier();   // RAW barrier: no vmcnt(0) drain
        // stage t1s for hc+1 (1 phase ahead, L2-hot), vt pf for hc+2 (2 phases)
        if (hc < 15) {
            #pragma unroll
            for (int i = 0; i < 4; ++i) {
                int j = (wv * 4 + i) * 64 + lane;
                int jj = j & 511;
                int r = jj >> 3, du = jj & 7, su = du ^ (r & 7);
                const ushort_t* src = ((j < 512) ? T1h : T1l)
                                      + (size_t)r * 1024 + (hc + 1) * 64 + su * 8;
                async16(&t1s[b ^ 1][(wv * 4 + i) * 512], src);
            }
        }
        if (hc < 14) {
            const ushort_t* srcv = vrow + (size_t)((hc + 2) * 64 + lrow) * 64 + cq;
            pf[b][0] = *(const uint4*)(srcv);
            pf[b][1] = *(const uint4*)(srcv + 8);
        }
        __builtin_amdgcn_sched_barrier(0);   // pin load issue above the MFMA cluster

        #pragma unroll
        for (int ys = 0; ys < 2; ++ys) {
            short8 af = *(const short8*)&vs[b][(wv * 16 + lm) * VS1 + ys * 32 + quad * 8];
            #pragma unroll
            for (int nt = 0; nt < 4; ++nt) {
                int sl = (((ys * 4 + quad) ^ (lm & 7)) * 8);   // swizzled 16B slot (shorts)
                short8 bh = *(const short8*)&t1s[b][(nt * 16 + lm) * 64 + sl];
                short8 bl = *(const short8*)&t1s[b][4096 + (nt * 16 + lm) * 64 + sl];
                acc[nt] = __builtin_amdgcn_mfma_f32_16x16x32_bf16(af, bh, acc[nt], 0, 0, 0);
                acc[nt] = __builtin_amdgcn_mfma_f32_16x16x32_bf16(af, bl, acc[nt], 0, 0, 0);
            }
        }
    }
    float* grow = gT + (size_t)x * 4096;
    #pragma unroll
    for (int nt = 0; nt < 4; ++nt)
        #pragma unroll
        for (int r = 0; r < 4; ++r)
            grow[(wv * 16 + quad * 4 + r) * 64 + nt * 16 + lm] = acc[nt][r];
}

// ---------------- F2
__global__ __launch_bounds__(256) void k_f2(const float* __restrict__ gT,
        const float* __restrict__ ct, const float* __restrict__ st,
        float* __restrict__ fpr, float* __restrict__ fpi) {
    int t = threadIdx.x;
    int cx = blockIdx.x;
    int cg = blockIdx.y;
    int k10 = blockIdx.z * 8;
    int l = t & 63;
    int q = t >> 6;
    int c = cg * 4 + q;
    int e = l & 1;
    int k2 = l >> 1;
    float acc[8];
    #pragma unroll
    for (int i = 0; i < 8; ++i) acc[i] = 0.f;
    for (int xi = 0; xi < 128; ++xi) {
        int x = cx * 128 + xi;
        float v = gT[(size_t)x * 4096 + c * 64 + l];
        float p = __shfl_xor(v, 1);
        float gr = e ? p : v;
        float gi = e ? v : p;
        float u  = e ? gi : gr;
        float w2 = e ? -gr : gi;
        float cb = ct[x], sb = st[x];
        int ph = (x * k10) & MASKN;
        float cr = ct[ph], sr = st[ph];
        #pragma unroll
        for (int j = 0; j < 8; ++j) {
            acc[j] = fmaf(u, cr, fmaf(w2, sr, acc[j]));
            float nc = fmaf(cr, cb, -sr * sb);
            float ns = fmaf(sr, cb, cr * sb);
            cr = nc; sr = ns;
        }
    }
    float* dst = e ? fpi : fpr;
    #pragma unroll
    for (int j = 0; j < 8; ++j)
        dst[(size_t)cx * 65536 + ((k10 + j) * 32 + k2) * 64 + c] = acc[j];
}

// ---------------- MIX
__global__ __launch_bounds__(64) void k_mix(const float* __restrict__ fpr, const float* __restrict__ fpi,
        const float* __restrict__ Rr, const float* __restrict__ Ri,
        float* __restrict__ Rfr, float* __restrict__ Rfi) {
    __shared__ float fr[64], fi[64];
    int m = blockIdx.x;
    int d = threadIdx.x;
    float sr = 0.f, si = 0.f;
    #pragma unroll
    for (int ch = 0; ch < 8; ++ch) {
        sr += fpr[(size_t)ch * 65536 + m * 64 + d];
        si += fpi[(size_t)ch * 65536 + m * 64 + d];
    }
    fr[d] = sr; fi[d] = si;
    __syncthreads();
    const float* Rrb = Rr + (size_t)m * 4096;
    const float* Rib = Ri + (size_t)m * 4096;
    float ar = 0.f, ai = 0.f;
    for (int c = 0; c < 64; ++c) {
        float rr = Rrb[c * 64 + d], ri = Rib[c * 64 + d];
        ar = fmaf(fr[c], rr, fmaf(-fi[c], ri, ar));
        ai = fmaf(fr[c], ri, fmaf(fi[c], rr, ai));
    }
    Rfr[m * 64 + d] = ar;
    Rfi[m * 64 + d] = ai;
}

// ---------------- I1: Bmat in k2-PARITY-SPLIT layout (matches T2p):
// Beo[n1][d][col]: col<32 holds even-k2 (re,im) pairs, col>=32 odd-k2.
// even k2: col = k2 + e; odd k2: col = (k2-1) + 32... both reduce to
// contiguous uint4 at [k20, k20+8) in each half for this thread's k20.
__global__ __launch_bounds__(256) void k_i1(const float* __restrict__ Rfr, const float* __restrict__ Rfi,
        const float* __restrict__ ctg, const float* __restrict__ stg,
        ushort_t* __restrict__ Bh, ushort_t* __restrict__ Bl) {
    __shared__ float ct[1024], st[1024];
    int t = threadIdx.x;
    #pragma unroll
    for (int i = 0; i < 4; ++i) { int j = t + 256 * i; ct[j] = ctg[j]; st[j] = stg[j]; }
    __syncthreads();
    int n1 = blockIdx.x;
    int d = t & 63;
    int k20 = (t >> 6) * 8;
    float br[8], bi[8];
    #pragma unroll
    for (int j = 0; j < 8; ++j) { br[j] = 0.f; bi[j] = 0.f; }
    int idx = 0;
    for (int k1 = 0; k1 < 32; ++k1) {
        float cc = ct[idx], ss = st[idx];
        idx = (idx + n1) & MASKN;
        #pragma unroll
        for (int j = 0; j < 8; ++j) {
            float rr = Rfr[(k1 * 32 + k20 + j) * 64 + d];
            float ri = Rfi[(k1 * 32 + k20 + j) * 64 + d];
            br[j] = fmaf(rr, cc, fmaf(-ri, ss, br[j]));
            bi[j] = fmaf(rr, ss, fmaf(ri, cc, bi[j]));
        }
    }
    union { uint4 u; ushort_t e[8]; } he, ho, le, lo_;
    #pragma unroll
    for (int j = 0; j < 8; ++j) {
        int k2 = k20 + j;
        float sc = (k2 == 0 ? 1.0f : 2.0f) * 9.5367431640625e-7f;   // 1/2^20
        float vr = br[j] * sc, vi = bi[j] * sc;
        ushort_t hr = f2bf(vr), hi2 = f2bf(vi);
        ushort_t lr = f2bf(vr - bf2f(hr)), li = f2bf(vi - bf2f(hi2));
        int p = (j >> 1) << 1;          // pair slot within half-block
        if (j & 1) { ho.e[p] = hr; ho.e[p + 1] = hi2; lo_.e[p] = lr; lo_.e[p + 1] = li; }
        else       { he.e[p] = hr; he.e[p + 1] = hi2; le.e[p]  = lr; le.e[p + 1]  = li; }
    }
    size_t base = ((size_t)n1 * 64 + d) * 64;
    *(uint4*)(Bh + base + k20)      = he.u;
    *(uint4*)(Bh + base + 32 + k20) = ho.u;
    *(uint4*)(Bl + base + k20)      = le.u;
    *(uint4*)(Bl + base + 32 + k20) = lo_.u;
}

// ---------------- I2 (MFMA, fused skip+inverse), round-12: DFT SYMMETRY.
// T2[n2+512][kk] = (-1)^k2 T2[n2][kk]  =>  with the k2-parity-split layout,
// C[n2] = E + O and C[n2+512] = E - O where E/O are K=32 contractions over
// the even/odd columns.  Per 128 output rows: MFMA 80->56 (-30%), A-side
// ds_read_b128 64->32 (-50%), frag loads 12->8; cost = 64 VALU adds + acc
// 16->64 VGPR.  Staging bytes/swizzle identical to R8; only column MEANING
// changed (k_fill_T2 + k_i1 write the permuted layouts).  8 iters of 64 low
// rows (n2<512) + their mirrors.  Zero main-loop barriers (R8 property kept).
template<bool FINAL>
__global__ __launch_bounds__(256, 4) void k_i2(ushort_t* __restrict__ vt,
        const ushort_t* __restrict__ Bh, const ushort_t* __restrict__ Bl,
        const ushort_t* __restrict__ T2h, const ushort_t* __restrict__ T2l,
        const ushort_t* __restrict__ wTh, const ushort_t* __restrict__ wTl,
        const float* __restrict__ Wp, const float* __restrict__ bp,
        float* __restrict__ out) {
    __shared__ __align__(16) ushort_t ab[16384];   // 32 KB: Beo-h|Beo-l|wTh|wTl (swizzled)
    int t = threadIdx.x;
    int wv = t >> 6, lane = t & 63;
    int lm = lane & 15, quad = lane >> 4;
    int n1 = blockIdx.x;
    const ushort_t* Bhr = Bh + (size_t)n1 * 4096;
    const ushort_t* Blr = Bl + (size_t)n1 * 4096;

    // ---- stage A-side into LDS once: swizzled SOURCE (unit u of row r -> slot
    // u^(r&7)), linear dest (global_load_lds requirement) -- unchanged from R8
    {
        const ushort_t* s = (wv == 0) ? Bhr : (wv == 1) ? Blr : (wv == 2) ? wTh : wTl;
        #pragma unroll
        for (int i = 0; i < 8; ++i) {
            int j = i * 64 + lane;                 // 0..511 16B-units in this quarter
            int r = j >> 3, u = (j & 7) ^ (r & 7);
            async16(&ab[wv * 4096 + i * 512], s + r * 64 + u * 8);
        }
    }

    // thread's fixed low row (within 64-row group): nL = c*64 + n2b, nH = nL+512
    int n2b = wv * 16 + lm;
    const ushort_t* t2hb = T2h + (size_t)n2b * 64 + quad * 8;   // T2p row, E at +0 / O at +32
    const ushort_t* t2lb = T2l + (size_t)n2b * 64 + quad * 8;
    const ushort_t* vrdL = vt + ((size_t)n1 * 1024 + n2b) * 64 + quad * 8;
    const ushort_t* vrdH = vrdL + 32768;                        // +512 rows
    ushort_t*       vstL = vt + ((size_t)n1 * 1024 + n2b) * 64;
    ushort_t*       vstH = vstL + 32768;

    // ---- prefetch iter-0 operands into regs (double-buffered by c&1)
    short8 the[2], tho[2], tle[2], tlo[2], vL[2][2], vH[2][2];
    the[0] = *(const short8*)(t2hb);
    tho[0] = *(const short8*)(t2hb + 32);
    tle[0] = *(const short8*)(t2lb);
    tlo[0] = *(const short8*)(t2lb + 32);
    #pragma unroll
    for (int ks = 0; ks < 2; ++ks) {
        vL[0][ks] = *(const short8*)(vrdL + ks * 32);
        vH[0][ks] = *(const short8*)(vrdH + ks * 32);
    }
    float4 wpv[4];
    float bp0 = 0.f;
    if (FINAL) {
        bp0 = bp[0];
        #pragma unroll
        for (int mt = 0; mt < 4; ++mt) wpv[mt] = *(const float4*)&Wp[mt * 16 + quad * 4];
    }
    __syncthreads();   // the ONLY barrier: ab staged + visible

    int r7 = lm & 7;
    #pragma unroll
    for (int c = 0; c < 8; ++c) {
        int b = c & 1;
        // prefetch iter c+1 (vt rows first: deepest latency; then T2p, L2-hot)
        if (c < 7) {
            int nb = b ^ 1;
            #pragma unroll
            for (int ks = 0; ks < 2; ++ks) {
                vL[nb][ks] = *(const short8*)(vrdL + (size_t)(c + 1) * 4096 + ks * 32);
                vH[nb][ks] = *(const short8*)(vrdH + (size_t)(c + 1) * 4096 + ks * 32);
            }
            the[nb] = *(const short8*)(t2hb + (c + 1) * 4096);
            tho[nb] = *(const short8*)(t2hb + (c + 1) * 4096 + 32);
            tle[nb] = *(const short8*)(t2lb + (c + 1) * 4096);
            tlo[nb] = *(const short8*)(t2lb + (c + 1) * 4096 + 32);
        }
        __builtin_amdgcn_sched_barrier(0);   // keep prefetch issue above the MFMAs

        floatx4 aE[4], aO[4], aL[4], aH[4];
        #pragma unroll
        for (int mt = 0; mt < 4; ++mt) {
            aE[mt] = (floatx4)(0.f); aO[mt] = (floatx4)(0.f);
            aL[mt] = (floatx4)(0.f); aH[mt] = (floatx4)(0.f);
        }

        __builtin_amdgcn_s_setprio(1);
        // ---- spectral part: E (even-k2) and O (odd-k2), K=32 each
        {
            int slE = (quad ^ r7) * 8;          // units 0-3 region
            int slO = ((4 + quad) ^ r7) * 8;    // units 4-7 region
            #pragma unroll
            for (int mt = 0; mt < 4; ++mt) {
                int roE = (mt * 16 + lm) * 64 + slE;
                int roO = (mt * 16 + lm) * 64 + slO;
                short8 aeh = *(const short8*)&ab[roE];
                short8 ael = *(const short8*)&ab[4096 + roE];
                short8 aoh = *(const short8*)&ab[roO];
                short8 aol = *(const short8*)&ab[4096 + roO];
                aE[mt] = __builtin_amdgcn_mfma_f32_16x16x32_bf16(aeh, the[b], aE[mt], 0, 0, 0);
                aE[mt] = __builtin_amdgcn_mfma_f32_16x16x32_bf16(ael, the[b], aE[mt], 0, 0, 0);
                aE[mt] = __builtin_amdgcn_mfma_f32_16x16x32_bf16(aeh, tle[b], aE[mt], 0, 0, 0);
                aO[mt] = __builtin_amdgcn_mfma_f32_16x16x32_bf16(aoh, tho[b], aO[mt], 0, 0, 0);
                aO[mt] = __builtin_amdgcn_mfma_f32_16x16x32_bf16(aol, tho[b], aO[mt], 0, 0, 0);
                aO[mt] = __builtin_amdgcn_mfma_f32_16x16x32_bf16(aoh, tlo[b], aO[mt], 0, 0, 0);
            }
        }
        // ---- skip part: rows nL and nH, K=64 over c
        #pragma unroll
        for (int ks = 0; ks < 2; ++ks) {
            int sl = ((ks * 4 + quad) ^ r7) * 8;
            #pragma unroll
            for (int mt = 0; mt < 4; ++mt) {
                int ro = (mt * 16 + lm) * 64 + sl;
                short8 wh = *(const short8*)&ab[8192 + ro];
                short8 wl = *(const short8*)&ab[12288 + ro];
                aL[mt] = __builtin_amdgcn_mfma_f32_16x16x32_bf16(wh, vL[b][ks], aL[mt], 0, 0, 0);
                aL[mt] = __builtin_amdgcn_mfma_f32_16x16x32_bf16(wl, vL[b][ks], aL[mt], 0, 0, 0);
                aH[mt] = __builtin_amdgcn_mfma_f32_16x16x32_bf16(wh, vH[b][ks], aH[mt], 0, 0, 0);
                aH[mt] = __builtin_amdgcn_mfma_f32_16x16x32_bf16(wl, vH[b][ks], aH[mt], 0, 0, 0);
            }
        }
        __builtin_amdgcn_s_setprio(0);

        if (!FINAL) {
            #pragma unroll
            for (int mt = 0; mt < 4; ++mt) {
                floatx4 lo4 = aE[mt] + aO[mt] + aL[mt];   // C[nL]
                floatx4 hi4 = aE[mt] - aO[mt] + aH[mt];   // C[nL+512]
                uint2 wlo, whi;
                wlo.x = pk2bf(gelu_f(lo4[0]), gelu_f(lo4[1]));
                wlo.y = pk2bf(gelu_f(lo4[2]), gelu_f(lo4[3]));
                whi.x = pk2bf(gelu_f(hi4[0]), gelu_f(hi4[1]));
                whi.y = pk2bf(gelu_f(hi4[2]), gelu_f(hi4[3]));
                *(uint2*)(vstL + (size_t)c * 4096 + mt * 16 + quad * 4) = wlo;
                *(uint2*)(vstH + (size_t)c * 4096 + mt * 16 + quad * 4) = whi;
            }
        } else {
            float sL = 0.f, sH = 0.f;
            #pragma unroll
            for (int mt = 0; mt < 4; ++mt) {
                floatx4 lo4 = aE[mt] + aO[mt] + aL[mt];
                floatx4 hi4 = aE[mt] - aO[mt] + aH[mt];
                sL = fmaf(gelu_f(lo4[0]), wpv[mt].x, sL);
                sL = fmaf(gelu_f(lo4[1]), wpv[mt].y, sL);
                sL = fmaf(gelu_f(lo4[2]), wpv[mt].z, sL);
                sL = fmaf(gelu_f(lo4[3]), wpv[mt].w, sL);
                sH = fmaf(gelu_f(hi4[0]), wpv[mt].x, sH);
                sH = fmaf(gelu_f(hi4[1]), wpv[mt].y, sH);
                sH = fmaf(gelu_f(hi4[2]), wpv[mt].z, sH);
                sH = fmaf(gelu_f(hi4[3]), wpv[mt].w, sH);
            }
            sL += __shfl_xor(sL, 16); sL += __shfl_xor(sL, 32);
            sH += __shfl_xor(sH, 16); sH += __shfl_xor(sH, 32);
            if (quad == 0) {
                out[(size_t)n1 * 1024 + c * 64 + n2b] = sL + bp0;
                out[(size_t)n1 * 1024 + 512 + c * 64 + n2b] = sH + bp0;
            }
        }
    }
}

extern "C" void kernel_launch(void* const* d_in, const int* in_sizes, int n_in,
                              void* d_out, int out_size, void* d_ws, size_t ws_size,
                              hipStream_t stream) {
    const float* in  = (const float*)d_in[0];
    const float* Wsh = (const float*)d_in[1];
    const float* bsh = (const float*)d_in[2];
    const float* Wp  = (const float*)d_in[15];
    const float* bp  = (const float*)d_in[16];

    // workspace layout (~151.9 MB, proven to fit)
    char* wsb = (char*)d_ws;
    ushort_t* vt   = (ushort_t*)wsb;                          // 1024*1024*64 bf16 = 134,217,728 B
    float* ctab = (float*)(wsb + 134217728);                  // 1024
    float* stab = ctab + 1024;                                // 1024
    float* gT   = stab + 1024;                                // 1024*64*64 f32 = 16 MB
    float* Rfr  = gT + 4194304;                               // 65536
    float* Rfi  = Rfr + 65536;                                // 65536
    ushort_t* T1h = (ushort_t*)(Rfi + 65536);                 // 64*1024
    ushort_t* T1l = T1h + 65536;
    ushort_t* T2h = T1l + 65536;                              // T2p: 512*64 (uses half)
    ushort_t* T2l = T2h + 65536;
    ushort_t* wTh = T2l + 65536;                              // 4*64*64
    ushort_t* wTl = wTh + 16384;
    ushort_t* Bh  = (ushort_t*)gT;                            // alias gT (dead after k_f2)
    ushort_t* Bl  = Bh + 4194304;
    float* fpr = (float*)d_out;                               // alias d_out (dead before final k_i2)
    float* fpi = fpr + 524288;

    k_fill_tw<<<4, 256, 0, stream>>>(ctab, stab);
    k_fill_T1<<<256, 256, 0, stream>>>(T1h, T1l);
    k_fill_T2<<<128, 256, 0, stream>>>(T2h, T2l);
    k_fill_wT<<<dim3(16, 4), 256, 0, stream>>>((const float*)d_in[5], (const float*)d_in[8],
                                               (const float*)d_in[11], (const float*)d_in[14], wTh, wTl);
    k_shallow<<<65536, 256, 0, stream>>>(in, Wsh, bsh, vt);
    for (int L = 0; L < 4; ++L) {
        const float* Rr = (const float*)d_in[3 + L * 3];
        const float* Ri = (const float*)d_in[4 + L * 3];
        k_f1<<<1024, 256, 0, stream>>>(vt, T1h, T1l, gT);
        k_f2<<<dim3(8, 16, 4), 256, 0, stream>>>(gT, ctab, stab, fpr, fpi);
        k_mix<<<1024, 64, 0, stream>>>(fpr, fpi, Rr, Ri, Rfr, Rfi);
        k_i1<<<1024, 256, 0, stream>>>(Rfr, Rfi, ctab, stab, Bh, Bl);
        if (L < 3) {
            k_i2<false><<<1024, 256, 0, stream>>>(vt, Bh, Bl, T2h, T2l,
                    wTh + L * 4096, wTl + L * 4096, nullptr, nullptr, nullptr);
        } else {
            k_i2<true><<<1024, 256, 0, stream>>>(vt, Bh, Bl, T2h, T2l,
                    wTh + L * 4096, wTl + L * 4096, Wp, bp, (float*)d_out);
        }
    }
}

// Round 13
// 733.493 us; speedup vs baseline: 1.1023x; 1.1023x over previous
//
#include <hip/hip_runtime.h>
#include <math.h>

#define MASKN 1023

typedef unsigned short ushort_t;
typedef __attribute__((ext_vector_type(8))) short short8;
typedef __attribute__((ext_vector_type(4))) float floatx4;
typedef __attribute__((ext_vector_type(4))) unsigned short us4v;   // 8B-aligned bf16x4

// tanh-form GELU; v_rcp_f32 instead of IEEE div (R8, ~1ulp, fine for approx gelu)
__device__ __forceinline__ float gelu_f(float x) {
    float x2 = x * x;
    float inner = fmaf(0.044715f * x, x2, x);
    float t = exp2f(inner * -2.302089214f);   // 2^(-2*0.7978845608*log2(e)*inner)
    return x * __builtin_amdgcn_rcpf(1.0f + t);
}

// ---- bf16 storage helpers (compute stays fp32) ----
__device__ __forceinline__ float bf2f(ushort_t h) {
    return __uint_as_float(((unsigned int)h) << 16);
}
__device__ __forceinline__ ushort_t f2bf(float f) {
    unsigned int u = __float_as_uint(f);
    u += 0x7FFFu + ((u >> 16) & 1u);   // round to nearest even
    return (ushort_t)(u >> 16);
}
struct us4 { ushort_t x, y, z, w; };

// pack 2 f32 -> 2 bf16 in ONE v_cvt_pk_bf16_f32 (RNE, same as manual path)
__device__ __forceinline__ unsigned int pk2bf(float lo, float hi) {
    unsigned int r;
    asm("v_cvt_pk_bf16_f32 %0, %1, %2" : "=v"(r) : "v"(lo), "v"(hi));
    return r;
}

__device__ __forceinline__ void st4(ushort_t* p, float4 v) {
    uint2 w;
    w.x = pk2bf(v.x, v.y);
    w.y = pk2bf(v.z, v.w);
    *(uint2*)p = w;
}

// async global->LDS, 16 B per lane; LDS dest = wave-uniform base + lane*16 (HW),
// global src is PER-LANE (this is how the swizzled staging works).
__device__ __forceinline__ void async16(ushort_t* l, const ushort_t* g) {
    __builtin_amdgcn_global_load_lds(
        (const __attribute__((address_space(1))) void*)g,
        (__attribute__((address_space(3))) void*)l, 16, 0, 0);
}

// ---------------- twiddle step table for k_f2 / k_i1
__global__ void k_fill_tw(float* __restrict__ ct, float* __restrict__ st) {
    int j = blockIdx.x * 256 + threadIdx.x;   // 0..1023
    float ang = (float)j * (6.283185307179586f / 1024.0f);
    float s, c;
    sincosf(ang, &s, &c);
    ct[j] = c; st[j] = s;
}

// ---------------- T1 table
__global__ void k_fill_T1(ushort_t* __restrict__ T1h, ushort_t* __restrict__ T1l) {
    int idx = blockIdx.x * 256 + threadIdx.x;   // 0..65535
    int k2p = idx >> 10, y = idx & 1023;
    int k2 = k2p >> 1;
    float ang = (float)((k2 * y) & MASKN) * (6.283185307179586f / 1024.0f);
    float s, c;
    sincosf(ang, &s, &c);
    float v = (k2p & 1) ? -s : c;
    ushort_t h = f2bf(v);
    T1h[idx] = h;
    T1l[idx] = f2bf(v - bf2f(h));
}

// ---------------- T2 table: T2[n2][kk]  (R11 original layout, reverted from R12)
__global__ void k_fill_T2(ushort_t* __restrict__ T2h, ushort_t* __restrict__ T2l) {
    int idx = blockIdx.x * 256 + threadIdx.x;   // 0..65535
    int n2 = idx >> 6, kk = idx & 63;
    int k2 = kk >> 1;
    float ang = (float)((k2 * n2) & MASKN) * (6.283185307179586f / 1024.0f);
    float s, c;
    sincosf(ang, &s, &c);
    float v = (kk & 1) ? -s : c;
    ushort_t h = f2bf(v);
    T2h[idx] = h;
    T2l[idx] = f2bf(v - bf2f(h));
}

// ---------------- wT tables: wT[l][d][c] = w_l[c][d], hi/lo
__global__ void k_fill_wT(const float* __restrict__ w1, const float* __restrict__ w2,
        const float* __restrict__ w3, const float* __restrict__ w4,
        ushort_t* __restrict__ wTh, ushort_t* __restrict__ wTl) {
    int l = blockIdx.y;
    int i = blockIdx.x * 256 + threadIdx.x;   // 0..4095
    int d = i >> 6, c = i & 63;
    const float* w = (l == 0) ? w1 : (l == 1) ? w2 : (l == 2) ? w3 : w4;
    float v = w[c * 64 + d];
    ushort_t h = f2bf(v);
    wTh[l * 4096 + i] = h;
    wTl[l * 4096 + i] = f2bf(v - bf2f(h));
}

// ---------------- shallow
__global__ __launch_bounds__(256) void k_shallow(const float* __restrict__ in,
        const float* __restrict__ Wsh, const float* __restrict__ bsh,
        ushort_t* __restrict__ vt) {
    int tid = blockIdx.x * 256 + threadIdx.x;
    int p = tid >> 4, c0 = (tid & 15) << 2;
    float a0 = in[p * 2], a1 = in[p * 2 + 1];
    float4 w0 = *(const float4*)&Wsh[c0];
    float4 w1 = *(const float4*)&Wsh[64 + c0];
    float4 b  = *(const float4*)&bsh[c0];
    float4 r;
    r.x = gelu_f(fmaf(a0, w0.x, fmaf(a1, w1.x, b.x)));
    r.y = gelu_f(fmaf(a0, w0.y, fmaf(a1, w1.y, b.y)));
    r.z = gelu_f(fmaf(a0, w0.z, fmaf(a1, w1.z, b.z)));
    r.w = gelu_f(fmaf(a0, w0.w, fmaf(a1, w1.w, b.w)));
    st4(&vt[(size_t)p * 64 + c0], r);
}

// ---------------- F1 (MFMA): gT[x][c][k2p] = sum_y vt[x][y][c] * T1[k2p][y]
// Round-13: X-PAIRING. k_f1 was 16 barriers/block with only 16 MFMA/wave per
// phase (historic MfmaUtil 5-10%) -- rendezvous + t1s staging amortized over
// too little compute.  Each block now processes TWO x values sharing the SAME
// T1 staging and the SAME barriers: 32 MFMA/wave per phase, t1s L2 traffic
// halved, ds-read:MFMA ratio 20:32 (was 18:16).  Counted-vmcnt pipeline (R9)
// kept: pf per chunk is now 4 loads -> steady-state wait vmcnt(4).
// LDS 32K (t1s x2) + 36K (vs 2buf x 2x) = 68 KB -> 2 blocks/CU; grid 512.
#define VS1 72   // vs row stride in shorts (144 B -> bank 4*lm, 2-way = free)
__global__ __launch_bounds__(256, 2) void k_f1(const ushort_t* __restrict__ vt,
        const ushort_t* __restrict__ T1h, const ushort_t* __restrict__ T1l,
        float* __restrict__ gT) {
    __shared__ __align__(16) ushort_t t1s[2][8192];          // [buf][h|l] shorts
    __shared__ __align__(16) ushort_t vs[2][2][64 * VS1];    // [buf][x][c][y]
    int t = threadIdx.x;
    int x0 = blockIdx.x * 2;
    int wv = t >> 6, lane = t & 63;
    int lm = lane & 15, quad = lane >> 4;
    int lrow = t & 63, cq = (t >> 6) * 16;               // staging map: 64 y-rows x 4 c-quarters
    const ushort_t* vrow0 = vt + (size_t)x0 * 65536;
    const ushort_t* vrow1 = vrow0 + 65536;

    floatx4 acc[2][4];
    #pragma unroll
    for (int xi = 0; xi < 2; ++xi)
        #pragma unroll
        for (int nt = 0; nt < 4; ++nt) acc[xi][nt] = (floatx4)(0.f);

    uint4 pf[2][2][2];   // [chunk parity][x][half]; loaded 2 chunks ahead
    // prologue: t1s(0) stage FIRST (oldest in queue), then pf ch0/ch1 both x
    #pragma unroll
    for (int i = 0; i < 4; ++i) {
        int j = (wv * 4 + i) * 64 + lane;            // 0..1023 16B-units (h then l)
        int jj = j & 511;
        int r = jj >> 3, du = jj & 7, su = du ^ (r & 7);
        const ushort_t* src = ((j < 512) ? T1h : T1l) + (size_t)r * 1024 + su * 8;
        async16(&t1s[0][(wv * 4 + i) * 512], src);
    }
    __builtin_amdgcn_sched_barrier(0);
    {
        const ushort_t* s00 = vrow0 + (size_t)lrow * 64 + cq;
        pf[0][0][0] = *(const uint4*)(s00);
        pf[0][0][1] = *(const uint4*)(s00 + 8);
        const ushort_t* s01 = vrow1 + (size_t)lrow * 64 + cq;
        pf[0][1][0] = *(const uint4*)(s01);
        pf[0][1][1] = *(const uint4*)(s01 + 8);
        const ushort_t* s10 = vrow0 + (size_t)(64 + lrow) * 64 + cq;
        pf[1][0][0] = *(const uint4*)(s10);
        pf[1][0][1] = *(const uint4*)(s10 + 8);
        const ushort_t* s11 = vrow1 + (size_t)(64 + lrow) * 64 + cq;
        pf[1][1][0] = *(const uint4*)(s11);
        pf[1][1][1] = *(const uint4*)(s11 + 8);
    }
    __builtin_amdgcn_sched_barrier(0);

    for (int hc = 0; hc < 16; ++hc) {
        int b = hc & 1;
        // scatter pf[b] (chunk hc, both x) transposed into vs[b][x]
        // (compiler inserts the precise vmcnt wait for the 4 pf loads)
        #pragma unroll
        for (int xi = 0; xi < 2; ++xi)
            #pragma unroll
            for (int i = 0; i < 2; ++i) {
                union { uint4 u; ushort_t e[8]; } uv;
                uv.u = pf[b][xi][i];
                #pragma unroll
                for (int j = 0; j < 8; ++j)
                    vs[b][xi][(cq + i * 8 + j) * VS1 + lrow] = uv.e[j];
            }
        __builtin_amdgcn_sched_barrier(0);
        // T4 counted wait: complete t1s[b] (staged last iter); leave chunk
        // hc+1's 4 vt loads in flight (none exist on the last iter).
        if (hc < 15) asm volatile("s_waitcnt vmcnt(4)" ::: "memory");
        else         asm volatile("s_waitcnt vmcnt(0)" ::: "memory");
        __builtin_amdgcn_sched_barrier(0);
        __builtin_amdgcn_s_barrier();   // RAW barrier: no vmcnt(0) drain
        // stage t1s for hc+1 (1 phase ahead, L2-hot), vt pf for hc+2 (2 phases)
        if (hc < 15) {
            #pragma unroll
            for (int i = 0; i < 4; ++i) {
                int j = (wv * 4 + i) * 64 + lane;
                int jj = j & 511;
                int r = jj >> 3, du = jj & 7, su = du ^ (r & 7);
                const ushort_t* src = ((j < 512) ? T1h : T1l)
                                      + (size_t)r * 1024 + (hc + 1) * 64 + su * 8;
                async16(&t1s[b ^ 1][(wv * 4 + i) * 512], src);
            }
        }
        if (hc < 14) {
            const ushort_t* s0 = vrow0 + (size_t)((hc + 2) * 64 + lrow) * 64 + cq;
            pf[b][0][0] = *(const uint4*)(s0);
            pf[b][0][1] = *(const uint4*)(s0 + 8);
            const ushort_t* s1 = vrow1 + (size_t)((hc + 2) * 64 + lrow) * 64 + cq;
            pf[b][1][0] = *(const uint4*)(s1);
            pf[b][1][1] = *(const uint4*)(s1 + 8);
        }
        __builtin_amdgcn_sched_barrier(0);   // pin load issue above the MFMA cluster

        #pragma unroll
        for (int ys = 0; ys < 2; ++ys) {
            short8 af0 = *(const short8*)&vs[b][0][(wv * 16 + lm) * VS1 + ys * 32 + quad * 8];
            short8 af1 = *(const short8*)&vs[b][1][(wv * 16 + lm) * VS1 + ys * 32 + quad * 8];
            #pragma unroll
            for (int nt = 0; nt < 4; ++nt) {
                int sl = (((ys * 4 + quad) ^ (lm & 7)) * 8);   // swizzled 16B slot (shorts)
                short8 bh = *(const short8*)&t1s[b][(nt * 16 + lm) * 64 + sl];
                short8 bl = *(const short8*)&t1s[b][4096 + (nt * 16 + lm) * 64 + sl];
                acc[0][nt] = __builtin_amdgcn_mfma_f32_16x16x32_bf16(af0, bh, acc[0][nt], 0, 0, 0);
                acc[0][nt] = __builtin_amdgcn_mfma_f32_16x16x32_bf16(af0, bl, acc[0][nt], 0, 0, 0);
                acc[1][nt] = __builtin_amdgcn_mfma_f32_16x16x32_bf16(af1, bh, acc[1][nt], 0, 0, 0);
                acc[1][nt] = __builtin_amdgcn_mfma_f32_16x16x32_bf16(af1, bl, acc[1][nt], 0, 0, 0);
            }
        }
    }
    #pragma unroll
    for (int xi = 0; xi < 2; ++xi) {
        float* grow = gT + (size_t)(x0 + xi) * 4096;
        #pragma unroll
        for (int nt = 0; nt < 4; ++nt)
            #pragma unroll
            for (int r = 0; r < 4; ++r)
                grow[(wv * 16 + quad * 4 + r) * 64 + nt * 16 + lm] = acc[xi][nt][r];
    }
}

// ---------------- F2
__global__ __launch_bounds__(256) void k_f2(const float* __restrict__ gT,
        const float* __restrict__ ct, const float* __restrict__ st,
        float* __restrict__ fpr, float* __restrict__ fpi) {
    int t = threadIdx.x;
    int cx = blockIdx.x;
    int cg = blockIdx.y;
    int k10 = blockIdx.z * 8;
    int l = t & 63;
    int q = t >> 6;
    int c = cg * 4 + q;
    int e = l & 1;
    int k2 = l >> 1;
    float acc[8];
    #pragma unroll
    for (int i = 0; i < 8; ++i) acc[i] = 0.f;
    for (int xi = 0; xi < 128; ++xi) {
        int x = cx * 128 + xi;
        float v = gT[(size_t)x * 4096 + c * 64 + l];
        float p = __shfl_xor(v, 1);
        float gr = e ? p : v;
        float gi = e ? v : p;
        float u  = e ? gi : gr;
        float w2 = e ? -gr : gi;
        float cb = ct[x], sb = st[x];
        int ph = (x * k10) & MASKN;
        float cr = ct[ph], sr = st[ph];
        #pragma unroll
        for (int j = 0; j < 8; ++j) {
            acc[j] = fmaf(u, cr, fmaf(w2, sr, acc[j]));
            float nc = fmaf(cr, cb, -sr * sb);
            float ns = fmaf(sr, cb, cr * sb);
            cr = nc; sr = ns;
        }
    }
    float* dst = e ? fpi : fpr;
    #pragma unroll
    for (int j = 0; j < 8; ++j)
        dst[(size_t)cx * 65536 + ((k10 + j) * 32 + k2) * 64 + c] = acc[j];
}

// ---------------- MIX
__global__ __launch_bounds__(64) void k_mix(const float* __restrict__ fpr, const float* __restrict__ fpi,
        const float* __restrict__ Rr, const float* __restrict__ Ri,
        float* __restrict__ Rfr, float* __restrict__ Rfi) {
    __shared__ float fr[64], fi[64];
    int m = blockIdx.x;
    int d = threadIdx.x;
    float sr = 0.f, si = 0.f;
    #pragma unroll
    for (int ch = 0; ch < 8; ++ch) {
        sr += fpr[(size_t)ch * 65536 + m * 64 + d];
        si += fpi[(size_t)ch * 65536 + m * 64 + d];
    }
    fr[d] = sr; fi[d] = si;
    __syncthreads();
    const float* Rrb = Rr + (size_t)m * 4096;
    const float* Rib = Ri + (size_t)m * 4096;
    float ar = 0.f, ai = 0.f;
    for (int c = 0; c < 64; ++c) {
        float rr = Rrb[c * 64 + d], ri = Rib[c * 64 + d];
        ar = fmaf(fr[c], rr, fmaf(-fi[c], ri, ar));
        ai = fmaf(fr[c], ri, fmaf(fi[c], rr, ai));
    }
    Rfr[m * 64 + d] = ar;
    Rfi[m * 64 + d] = ai;
}

// ---------------- I1: Bmat[n1][d][kk]  (R11 original layout, reverted)
__global__ __launch_bounds__(256) void k_i1(const float* __restrict__ Rfr, const float* __restrict__ Rfi,
        const float* __restrict__ ctg, const float* __restrict__ stg,
        ushort_t* __restrict__ Bh, ushort_t* __restrict__ Bl) {
    __shared__ float ct[1024], st[1024];
    int t = threadIdx.x;
    #pragma unroll
    for (int i = 0; i < 4; ++i) { int j = t + 256 * i; ct[j] = ctg[j]; st[j] = stg[j]; }
    __syncthreads();
    int n1 = blockIdx.x;
    int d = t & 63;
    int k20 = (t >> 6) * 8;
    float br[8], bi[8];
    #pragma unroll
    for (int j = 0; j < 8; ++j) { br[j] = 0.f; bi[j] = 0.f; }
    int idx = 0;
    for (int k1 = 0; k1 < 32; ++k1) {
        float cc = ct[idx], ss = st[idx];
        idx = (idx + n1) & MASKN;
        #pragma unroll
        for (int j = 0; j < 8; ++j) {
            float rr = Rfr[(k1 * 32 + k20 + j) * 64 + d];
            float ri = Rfi[(k1 * 32 + k20 + j) * 64 + d];
            br[j] = fmaf(rr, cc, fmaf(-ri, ss, br[j]));
            bi[j] = fmaf(rr, ss, fmaf(ri, cc, bi[j]));
        }
    }
    union { uint4 u[2]; ushort_t e[16]; } hh, ll;
    #pragma unroll
    for (int j = 0; j < 8; ++j) {
        int k2 = k20 + j;
        float sc = (k2 == 0 ? 1.0f : 2.0f) * 9.5367431640625e-7f;   // 1/2^20
        float vr = br[j] * sc, vi = bi[j] * sc;
        ushort_t hr = f2bf(vr), hi2 = f2bf(vi);
        hh.e[2 * j] = hr;          hh.e[2 * j + 1] = hi2;
        ll.e[2 * j] = f2bf(vr - bf2f(hr));
        ll.e[2 * j + 1] = f2bf(vi - bf2f(hi2));
    }
    size_t base = ((size_t)n1 * 64 + d) * 64 + 2 * k20;
    *(uint4*)(Bh + base) = hh.u[0];
    *(uint4*)(Bh + base + 8) = hh.u[1];
    *(uint4*)(Bl + base) = ll.u[0];
    *(uint4*)(Bl + base + 8) = ll.u[1];
}

// ---------------- I2 (MFMA, fused skip+inverse): EXACT R8 structure, reverted.
// R12's DFT-symmetry split doubled FETCH (76->154 MB: the L/H dual-region vt
// read pattern destroyed L3 streaming locality) and halved MfmaUtil -> 100 us.
// Three structural attempts (R9/R10/R12) all failed; R8 is the local optimum:
// 78.5 us, VGPR 48, 4 blocks/CU, barrier-free main loop.
template<bool FINAL>
__global__ __launch_bounds__(256, 4) void k_i2(ushort_t* __restrict__ vt,
        const ushort_t* __restrict__ Bh, const ushort_t* __restrict__ Bl,
        const ushort_t* __restrict__ T2h, const ushort_t* __restrict__ T2l,
        const ushort_t* __restrict__ wTh, const ushort_t* __restrict__ wTl,
        const float* __restrict__ Wp, const float* __restrict__ bp,
        float* __restrict__ out) {
    __shared__ __align__(16) ushort_t ab[16384];   // 32 KB: Bh|Bl|wTh|wTl (swizzled)
    int t = threadIdx.x;
    int wv = t >> 6, lane = t & 63;
    int lm = lane & 15, quad = lane >> 4;
    int n1 = blockIdx.x;
    const ushort_t* Bhr = Bh + (size_t)n1 * 4096;
    const ushort_t* Blr = Bl + (size_t)n1 * 4096;

    // ---- stage A-side into LDS once: swizzled SOURCE (unit u of row r -> slot
    // u^(r&7)), linear dest (global_load_lds requirement)
    {
        const ushort_t* s = (wv == 0) ? Bhr : (wv == 1) ? Blr : (wv == 2) ? wTh : wTl;
        #pragma unroll
        for (int i = 0; i < 8; ++i) {
            int j = i * 64 + lane;                 // 0..511 16B-units in this quarter
            int r = j >> 3, u = (j & 7) ^ (r & 7);
            async16(&ab[wv * 4096 + i * 512], s + r * 64 + u * 8);
        }
    }

    // thread's fixed n2 column (within chunk): row n2b + c*64
    int n2b = wv * 16 + lm;
    const ushort_t* t2hp = T2h + n2b * 64 + quad * 8;
    const ushort_t* t2lp = T2l + n2b * 64 + quad * 8;
    const ushort_t* vrd  = vt + ((size_t)n1 * 1024 + n2b) * 64 + quad * 8;
    ushort_t*       vst  = vt + ((size_t)n1 * 1024 + n2b) * 64;

    // ---- prefetch chunk-0 operands into regs (double-buffered by c&1)
    short8 th[2][2], tl[2][2], vv[2][2];
    #pragma unroll
    for (int ks = 0; ks < 2; ++ks) {
        th[0][ks] = *(const short8*)(t2hp + ks * 32);
        tl[0][ks] = *(const short8*)(t2lp + ks * 32);
        vv[0][ks] = *(const short8*)(vrd + ks * 32);
    }
    float4 wpv[4];
    float bp0 = 0.f;
    if (FINAL) {
        bp0 = bp[0];
        #pragma unroll
        for (int mt = 0; mt < 4; ++mt) wpv[mt] = *(const float4*)&Wp[mt * 16 + quad * 4];
    }
    __syncthreads();   // the ONLY barrier: ab staged + visible

    int r7 = lm & 7;
    #pragma unroll
    for (int c = 0; c < 16; ++c) {
        // prefetch chunk c+1 (T2 rows + vt skip), a full chunk ahead
        if (c < 15) {
            #pragma unroll
            for (int ks = 0; ks < 2; ++ks) {
                th[(c + 1) & 1][ks] = *(const short8*)(t2hp + (c + 1) * 4096 + ks * 32);
                tl[(c + 1) & 1][ks] = *(const short8*)(t2lp + (c + 1) * 4096 + ks * 32);
                vv[(c + 1) & 1][ks] = *(const short8*)(vrd + (size_t)(c + 1) * 4096 + ks * 32);
            }
        }
        __builtin_amdgcn_sched_barrier(0);   // keep prefetch issue above the MFMAs

        floatx4 acc[4];
        #pragma unroll
        for (int mt = 0; mt < 4; ++mt) acc[mt] = (floatx4)(0.f);

        __builtin_amdgcn_s_setprio(1);
        #pragma unroll
        for (int ks = 0; ks < 2; ++ks) {
            int sl = ((ks * 4 + quad) ^ r7) * 8;
            #pragma unroll
            for (int mt = 0; mt < 4; ++mt) {
                int ro = (mt * 16 + lm) * 64 + sl;
                short8 ah = *(const short8*)&ab[ro];
                short8 al = *(const short8*)&ab[4096 + ro];
                short8 wh = *(const short8*)&ab[8192 + ro];
                short8 wl = *(const short8*)&ab[12288 + ro];
                acc[mt] = __builtin_amdgcn_mfma_f32_16x16x32_bf16(ah, th[c & 1][ks], acc[mt], 0, 0, 0);
                acc[mt] = __builtin_amdgcn_mfma_f32_16x16x32_bf16(al, th[c & 1][ks], acc[mt], 0, 0, 0);
                acc[mt] = __builtin_amdgcn_mfma_f32_16x16x32_bf16(ah, tl[c & 1][ks], acc[mt], 0, 0, 0);
                acc[mt] = __builtin_amdgcn_mfma_f32_16x16x32_bf16(wh, vv[c & 1][ks], acc[mt], 0, 0, 0);
                acc[mt] = __builtin_amdgcn_mfma_f32_16x16x32_bf16(wl, vv[c & 1][ks], acc[mt], 0, 0, 0);
            }
        }
        __builtin_amdgcn_s_setprio(0);

        if (!FINAL) {
            // thread owns n2 = c*64 + n2b, d = mt*16 + quad*4 + r -> 4x 8B stores
            #pragma unroll
            for (int mt = 0; mt < 4; ++mt) {
                uint2 w;
                w.x = pk2bf(gelu_f(acc[mt][0]), gelu_f(acc[mt][1]));
                w.y = pk2bf(gelu_f(acc[mt][2]), gelu_f(acc[mt][3]));
                *(uint2*)(vst + (size_t)c * 4096 + mt * 16 + quad * 4) = w;
            }
        } else {
            float s = 0.f;
            #pragma unroll
            for (int mt = 0; mt < 4; ++mt) {
                s = fmaf(gelu_f(acc[mt][0]), wpv[mt].x, s);
                s = fmaf(gelu_f(acc[mt][1]), wpv[mt].y, s);
                s = fmaf(gelu_f(acc[mt][2]), wpv[mt].z, s);
                s = fmaf(gelu_f(acc[mt][3]), wpv[mt].w, s);
            }
            s += __shfl_xor(s, 16);
            s += __shfl_xor(s, 32);
            if (quad == 0)
                out[(size_t)n1 * 1024 + c * 64 + n2b] = s + bp0;
        }
    }
}

extern "C" void kernel_launch(void* const* d_in, const int* in_sizes, int n_in,
                              void* d_out, int out_size, void* d_ws, size_t ws_size,
                              hipStream_t stream) {
    const float* in  = (const float*)d_in[0];
    const float* Wsh = (const float*)d_in[1];
    const float* bsh = (const float*)d_in[2];
    const float* Wp  = (const float*)d_in[15];
    const float* bp  = (const float*)d_in[16];

    // workspace layout (~151.9 MB, proven to fit)
    char* wsb = (char*)d_ws;
    ushort_t* vt   = (ushort_t*)wsb;                          // 1024*1024*64 bf16 = 134,217,728 B
    float* ctab = (float*)(wsb + 134217728);                  // 1024
    float* stab = ctab + 1024;                                // 1024
    float* gT   = stab + 1024;                                // 1024*64*64 f32 = 16 MB
    float* Rfr  = gT + 4194304;                               // 65536
    float* Rfi  = Rfr + 65536;                                // 65536
    ushort_t* T1h = (ushort_t*)(Rfi + 65536);                 // 64*1024
    ushort_t* T1l = T1h + 65536;
    ushort_t* T2h = T1l + 65536;                              // 1024*64
    ushort_t* T2l = T2h + 65536;
    ushort_t* wTh = T2l + 65536;                              // 4*64*64
    ushort_t* wTl = wTh + 16384;
    ushort_t* Bh  = (ushort_t*)gT;                            // alias gT (dead after k_f2)
    ushort_t* Bl  = Bh + 4194304;
    float* fpr = (float*)d_out;                               // alias d_out (dead before final k_i2)
    float* fpi = fpr + 524288;

    k_fill_tw<<<4, 256, 0, stream>>>(ctab, stab);
    k_fill_T1<<<256, 256, 0, stream>>>(T1h, T1l);
    k_fill_T2<<<256, 256, 0, stream>>>(T2h, T2l);
    k_fill_wT<<<dim3(16, 4), 256, 0, stream>>>((const float*)d_in[5], (const float*)d_in[8],
                                               (const float*)d_in[11], (const float*)d_in[14], wTh, wTl);
    k_shallow<<<65536, 256, 0, stream>>>(in, Wsh, bsh, vt);
    for (int L = 0; L < 4; ++L) {
        const float* Rr = (const float*)d_in[3 + L * 3];
        const float* Ri = (const float*)d_in[4 + L * 3];
        k_f1<<<512, 256, 0, stream>>>(vt, T1h, T1l, gT);
        k_f2<<<dim3(8, 16, 4), 256, 0, stream>>>(gT, ctab, stab, fpr, fpi);
        k_mix<<<1024, 64, 0, stream>>>(fpr, fpi, Rr, Ri, Rfr, Rfi);
        k_i1<<<1024, 256, 0, stream>>>(Rfr, Rfi, ctab, stab, Bh, Bl);
        if (L < 3) {
            k_i2<false><<<1024, 256, 0, stream>>>(vt, Bh, Bl, T2h, T2l,
                    wTh + L * 4096, wTl + L * 4096, nullptr, nullptr, nullptr);
        } else {
            k_i2<true><<<1024, 256, 0, stream>>>(vt, Bh, Bl, T2h, T2l,
                    wTh + L * 4096, wTl + L * 4096, Wp, bp, (float*)d_out);
        }
    }
}